// Round 9
// baseline (234.991 us; speedup 1.0000x reference)
//
#include <hip/hip_runtime.h>
#include <math.h>

// SimpleSSM: u(B,DI,L) f32, A(S), B_mat(S,DI), C_mat(DO,S), D_mat(DO,DI), h0(S)
#define BZ 8
#define DI 256
#define DS 512
#define DOUT 256
#define LL 4096
#define BS (BZ * DS)   // 4096
#define CH 128         // number of 32-wide l-chunks (round 9: split 64->128)
#define CT 32          // chunk length
#define XST 520        // X LDS row stride in ushorts (512 + 8 pad)

typedef __bf16 bf16x8 __attribute__((ext_vector_type(8)));
typedef float f32x4 __attribute__((ext_vector_type(4)));
typedef unsigned short us8 __attribute__((ext_vector_type(8)));

#define WAITV(n) asm volatile("s_waitcnt vmcnt(" #n ")" ::: "memory")
#define WAITL0   asm volatile("s_waitcnt lgkmcnt(0)" ::: "memory")
#define SB0      __builtin_amdgcn_sched_barrier(0)

__device__ __forceinline__ ushort f2b(float f) {
    union { float f; unsigned u; } v; v.f = f;
    unsigned r = v.u + 0x7FFFu + ((v.u >> 16) & 1u);
    return (ushort)(r >> 16);
}
__device__ __forceinline__ float b2f(ushort h) {
    union { unsigned u; float f; } v; v.u = ((unsigned)h) << 16;
    return v.f;
}

__device__ __forceinline__ void gload16(const void* g, ushort* l) {
    __builtin_amdgcn_global_load_lds(
        (const __attribute__((address_space(1))) unsigned int*)g,
        (__attribute__((address_space(3))) unsigned int*)l,
        16, 0, 0);
}

// ---------------------------------------------------------------------------
// k_prep: apow table (a^j, j=0..CT) + bf16 conversion of Bm/Cm. 256 blocks.
// ---------------------------------------------------------------------------
__global__ __launch_bounds__(256) void k_prep(const float* __restrict__ Au,
                                              float* __restrict__ apow,
                                              const float* __restrict__ Bm,
                                              const float* __restrict__ Cm,
                                              ushort* __restrict__ Bmb,
                                              ushort* __restrict__ Cmb) {
    const int t = blockIdx.x * 256 + threadIdx.x;
    const int n1 = DS * DI / 4, n2 = DOUT * DS / 4;
    if (t < n1) {
        float4 v = ((const float4*)Bm)[t];
        ushort4 o; o.x = f2b(v.x); o.y = f2b(v.y); o.z = f2b(v.z); o.w = f2b(v.w);
        ((ushort4*)Bmb)[t] = o;
    } else if (t < n1 + n2) {
        float4 v = ((const float4*)Cm)[t - n1];
        ushort4 o; o.x = f2b(v.x); o.y = f2b(v.y); o.z = f2b(v.z); o.w = f2b(v.w);
        ((ushort4*)Cmb)[t - n1] = o;
    }
    if (t < DS) {
        float x = Au[t];
        float sp = (x > 15.f) ? x : log1pf(expf(x));
        float ad = -sp;
        float p = 1.f;
        apow[t] = 1.f;
        for (int j = 1; j <= CT; ++j) { p *= ad; apow[j * DS + t] = p; }
    }
}

// ---------------------------------------------------------------------------
// k_finals: F_c[s] for ALL (c, b, s); ONE block per (chunk, b) with FULL
// s=512 -> u staged exactly ONCE grid-wide (round-8 grid staged each u tile
// 4x). Counted-vmcnt GEMM1 (verified round-8 structure) + in-register
// weighted reduce: F = a^(15-mrow) * (acc[0]*a16 + acc[1])   (l = ni*16+mrow,
// descending Horner), butterfly over mrow.
// LDS 17 KB: Uc 3x[32i][32l]f32 @0/2048/4096 ush; Bt 2x[32l][40] @6144/7424.
// Grid (CH, BZ) = 1024 blocks -> 4 blocks/CU.
// ---------------------------------------------------------------------------
__global__ __launch_bounds__(256, 4) void k_finals(const float* __restrict__ u,
                                                   const ushort* __restrict__ Bmb,
                                                   const float* __restrict__ apow,
                                                   float* __restrict__ finals) {
    __shared__ ushort smem[8704];
    const int tid = threadIdx.x;
    const int w = tid >> 6, lane = tid & 63;
    const int mrow = lane & 15, quad = lane >> 4;
    const int c0 = blockIdx.x, b = blockIdx.y;
    const int l0 = c0 * CT;

    f32x4 acc[8][2];
#pragma unroll
    for (int mi = 0; mi < 8; ++mi)
#pragma unroll
        for (int ni = 0; ni < 2; ++ni) acc[mi][ni] = (f32x4)0.f;

    // thread stages 16B: row i = tid>>3 (wave-private rows 8w..8w+7), l-quad tid&7
    const float* usrc = u + ((size_t)b * DI + (tid >> 3)) * LL + l0 + (tid & 7) * 4;

    auto stageU = [&](int it) {           // 1 vmcnt event; buffer it%3
        gload16(usrc + (size_t)(it * 32) * LL, smem + (it % 3) * 2048 + w * 512);
    };
    auto xposeU = [&](int it) {           // wave-private rows 8w..8w+7
        const float* uf = (const float*)&smem[(it % 3) * 2048];
        const int bto = 6144 + (it & 1) * 1280;
        const int r0 = 8 * w + (lane >> 5) * 4, cl = lane & 31;
        float v[4];
#pragma unroll
        for (int j = 0; j < 4; ++j) v[j] = uf[(r0 + j) * 32 + cl];
        ushort4 o; o.x = f2b(v[0]); o.y = f2b(v[1]); o.z = f2b(v[2]); o.w = f2b(v[3]);
        *(ushort4*)&smem[bto + cl * 40 + r0] = o;
    };

    stageU(0); stageU(1);
#pragma unroll
    for (int it = 0; it < DI / 32; ++it) {
        bf16x8 af[8];
#pragma unroll
        for (int mi = 0; mi < 8; ++mi)
            af[mi] = *(const bf16x8*)&Bmb[(size_t)(128 * w + mi * 16 + mrow) * DI + it * 32 + quad * 8];
        SB0;                               // af issued before stage/WAITV
        if (it + 2 < DI / 32) stageU(it + 2);
        if (it == 0) { WAITV(10); }        // drain stage(0)
        xposeU(it);
        WAITL0;
        __builtin_amdgcn_s_barrier();
        SB0;
        const int bto = 6144 + (it & 1) * 1280;
        bf16x8 bfr[2];
#pragma unroll
        for (int ni = 0; ni < 2; ++ni)
            bfr[ni] = *(const bf16x8*)&smem[bto + (ni * 16 + mrow) * 40 + quad * 8];
#pragma unroll
        for (int mi = 0; mi < 8; ++mi)
#pragma unroll
            for (int ni = 0; ni < 2; ++ni)
                acc[mi][ni] = __builtin_amdgcn_mfma_f32_16x16x32_bf16(af[mi], bfr[ni], acc[mi][ni], 0, 0, 0);
        WAITL0;
        __builtin_amdgcn_s_barrier();
        SB0;
    }

    // weighted reduce: F = a^(15-mrow) * (acc[0]*a16 + acc[1]); sum over mrow
    float F[8][4];
#pragma unroll
    for (int mi = 0; mi < 8; ++mi) {
        const int sb = 128 * w + mi * 16 + quad * 4;
        f32x4 a16 = *(const f32x4*)&apow[16 * DS + sb];
        f32x4 wgt = *(const f32x4*)&apow[(size_t)(15 - mrow) * DS + sb];
#pragma unroll
        for (int r = 0; r < 4; ++r)
            F[mi][r] = wgt[r] * (acc[mi][0][r] * a16[r] + acc[mi][1][r]);
    }
#pragma unroll
    for (int d = 1; d < 16; d <<= 1)
#pragma unroll
        for (int mi = 0; mi < 8; ++mi)
#pragma unroll
            for (int r = 0; r < 4; ++r)
                F[mi][r] += __shfl_xor(F[mi][r], d);
    if (mrow == 0) {
#pragma unroll
        for (int mi = 0; mi < 8; ++mi) {
            f32x4 o; o[0] = F[mi][0]; o[1] = F[mi][1]; o[2] = F[mi][2]; o[3] = F[mi][3];
            *(f32x4*)&finals[(size_t)c0 * BS + (size_t)b * DS + 128 * w + mi * 16 + quad * 4] = o;
        }
    }
}

// ---------------------------------------------------------------------------
// k_mainB: one 32-chunk per block: exact carry (batched finals) + GEMM1
// (counted-vmcnt) + batched scan + correction + GEMM2. CT=32 halves the X
// tile -> LDS 35.3 KB -> 4 blocks/CU (16 waves/CU; was 2 blocks -> the
// round-8 latency wall). Grid (CH, BZ) = 1024.
// LDS (ush): staging overlay Uc 3x2048 @0, Bt 2x1280 @6144 (inside X region);
// X [32][520] = [0,16640); crl f32[512] @16640. Total 35328 B.
// ---------------------------------------------------------------------------
__global__ __launch_bounds__(256, 4) void k_mainB(const float* __restrict__ u,
                                                  const ushort* __restrict__ Bmb,
                                                  const ushort* __restrict__ Cmb,
                                                  const float* __restrict__ apow,
                                                  const float* __restrict__ h0,
                                                  const float* __restrict__ finals,
                                                  float* __restrict__ Y) {
    __shared__ ushort smem[17664];        // 35328 B
    float* crl = (float*)&smem[16640];
    const int tid = threadIdx.x;
    const int w = tid >> 6, lane = tid & 63;
    const int mrow = lane & 15, quad = lane >> 4;
    const int c0 = blockIdx.x, b = blockIdx.y;
    const int l0 = c0 * CT;

    const float* usrc = u + ((size_t)b * DI + (tid >> 3)) * LL + l0 + (tid & 7) * 4;

    auto stageU = [&](int it) {
        gload16(usrc + (size_t)(it * 32) * LL, smem + (it % 3) * 2048 + w * 512);
    };
    auto xposeU = [&](int it) {
        const float* uf = (const float*)&smem[(it % 3) * 2048];
        const int bto = 6144 + (it & 1) * 1280;
        const int r0 = 8 * w + (lane >> 5) * 4, cl = lane & 31;
        float v[4];
#pragma unroll
        for (int j = 0; j < 4; ++j) v[j] = uf[(r0 + j) * 32 + cl];
        ushort4 o; o.x = f2b(v[0]); o.y = f2b(v[1]); o.z = f2b(v[2]); o.w = f2b(v[3]);
        *(ushort4*)&smem[bto + cl * 40 + r0] = o;
    };

    // ---- prologue staging, then exact carry chain under its latency -------
    stageU(0); stageU(1);
    {
        const float aT0 = apow[CT * DS + tid];          // a^32
        const float aT1 = apow[CT * DS + 256 + tid];
        float cva = h0[tid], cvb = h0[256 + tid];
        const float* fb = finals + (size_t)b * DS;
        int c = 0;
        for (; c + 8 <= c0; c += 8) {
            float fa[8], fc[8];
#pragma unroll
            for (int j = 0; j < 8; ++j) {
                fa[j] = fb[(size_t)(c + j) * BS + tid];
                fc[j] = fb[(size_t)(c + j) * BS + 256 + tid];
            }
#pragma unroll
            for (int j = 0; j < 8; ++j) {
                cva = aT0 * cva + fa[j];
                cvb = aT1 * cvb + fc[j];
            }
        }
        for (; c < c0; ++c) {
            cva = aT0 * cva + fb[(size_t)c * BS + tid];
            cvb = aT1 * cvb + fb[(size_t)c * BS + 256 + tid];
        }
        crl[tid] = cva; crl[256 + tid] = cvb;
    }

    // ---- GEMM1: Bu, s512 x l32, counted-vmcnt pipelined K-loop ------------
    f32x4 acc1[8][2];
#pragma unroll
    for (int mi = 0; mi < 8; ++mi)
#pragma unroll
        for (int ni = 0; ni < 2; ++ni) acc1[mi][ni] = (f32x4)0.f;

#pragma unroll
    for (int it = 0; it < DI / 32; ++it) {
        bf16x8 af[8];
#pragma unroll
        for (int mi = 0; mi < 8; ++mi)
            af[mi] = *(const bf16x8*)&Bmb[(size_t)(128 * w + mi * 16 + mrow) * DI + it * 32 + quad * 8];
        SB0;
        if (it + 2 < DI / 32) stageU(it + 2);
        if (it == 0) { WAITV(10); }
        xposeU(it);
        WAITL0;
        __builtin_amdgcn_s_barrier();
        SB0;
        const int bto = 6144 + (it & 1) * 1280;
        bf16x8 bfr[2];
#pragma unroll
        for (int ni = 0; ni < 2; ++ni)
            bfr[ni] = *(const bf16x8*)&smem[bto + (ni * 16 + mrow) * 40 + quad * 8];
#pragma unroll
        for (int mi = 0; mi < 8; ++mi)
#pragma unroll
            for (int ni = 0; ni < 2; ++ni)
                acc1[mi][ni] = __builtin_amdgcn_mfma_f32_16x16x32_bf16(af[mi], bfr[ni], acc1[mi][ni], 0, 0, 0);
        WAITL0;
        __builtin_amdgcn_s_barrier();
        SB0;
    }
    __syncthreads();   // drain before X-store overwrites staging region

    // ---- store acc1 -> X[l][s] (bf16, transposed) -------------------------
#pragma unroll
    for (int mi = 0; mi < 8; ++mi) {
        const int sloc = 128 * w + mi * 16 + quad * 4;
#pragma unroll
        for (int ni = 0; ni < 2; ++ni) {
            const int lloc = ni * 16 + mrow;
            f32x4 v = acc1[mi][ni];
            ushort4 o; o.x = f2b(v[0]); o.y = f2b(v[1]); o.z = f2b(v[2]); o.w = f2b(v[3]);
            *(ushort4*)&smem[lloc * XST + sloc] = o;
        }
    }
    __syncthreads();

    // ---- scan over l (32 steps), LDS reads batched by 8 -------------------
    {
        const float2 av = *(const float2*)&apow[DS + 2 * tid];
        float x0 = 0.f, x1 = 0.f;
        unsigned* pp = (unsigned*)&smem[2 * tid];
#pragma unroll
        for (int bt = 0; bt < CT / 8; ++bt) {
            unsigned v[8];
#pragma unroll
            for (int j = 0; j < 8; ++j) v[j] = pp[(bt * 8 + j) * (XST / 2)];
#pragma unroll
            for (int j = 0; j < 8; ++j) {
                x0 = av.x * x0 + b2f((ushort)(v[j] & 0xFFFFu));
                x1 = av.y * x1 + b2f((ushort)(v[j] >> 16));
                v[j] = (unsigned)f2b(x0) | ((unsigned)f2b(x1) << 16);
            }
#pragma unroll
            for (int j = 0; j < 8; ++j) pp[(bt * 8 + j) * (XST / 2)] = v[j];
        }
    }
    __syncthreads();

    // ---- correction: X[l][s] += apow[l+1][s] * crl[s] ---------------------
    {
        const int lr = tid >> 3, g = tid & 7;   // 32 rows x 8 groups
#pragma unroll
        for (int cc = 0; cc < 8; ++cc) {
            const int s = g * 64 + cc * 8;
            us8 x = *(const us8*)&smem[lr * XST + s];
            float4 a1 = *(const float4*)&apow[(size_t)(lr + 1) * DS + s];
            float4 a2 = *(const float4*)&apow[(size_t)(lr + 1) * DS + s + 4];
            float4 c1 = *(const float4*)&crl[s];
            float4 c2 = *(const float4*)&crl[s + 4];
            us8 o;
            o[0] = f2b(b2f(x[0]) + a1.x * c1.x);
            o[1] = f2b(b2f(x[1]) + a1.y * c1.y);
            o[2] = f2b(b2f(x[2]) + a1.z * c1.z);
            o[3] = f2b(b2f(x[3]) + a1.w * c1.w);
            o[4] = f2b(b2f(x[4]) + a2.x * c2.x);
            o[5] = f2b(b2f(x[5]) + a2.y * c2.y);
            o[6] = f2b(b2f(x[6]) + a2.z * c2.z);
            o[7] = f2b(b2f(x[7]) + a2.w * c2.w);
            *(us8*)&smem[lr * XST + s] = o;
        }
    }
    __syncthreads();

    // ---- GEMM2: Y = C @ Xc, o256 x l32, K = DS (no barriers) --------------
    f32x4 acc2[2][4];
#pragma unroll
    for (int mi = 0; mi < 2; ++mi)
#pragma unroll
        for (int ni = 0; ni < 4; ++ni) acc2[mi][ni] = (f32x4)0.f;

#pragma unroll
    for (int it = 0; it < DS / 32; ++it) {
        bf16x8 af2[2], bfr2[4];
#pragma unroll
        for (int mi = 0; mi < 2; ++mi)
            af2[mi] = *(const bf16x8*)&smem[(mi * 16 + mrow) * XST + it * 32 + quad * 8];
#pragma unroll
        for (int ni = 0; ni < 4; ++ni)
            bfr2[ni] = *(const bf16x8*)&Cmb[(size_t)(64 * w + ni * 16 + mrow) * DS + it * 32 + quad * 8];
#pragma unroll
        for (int mi = 0; mi < 2; ++mi)
#pragma unroll
            for (int ni = 0; ni < 4; ++ni)
                acc2[mi][ni] = __builtin_amdgcn_mfma_f32_16x16x32_bf16(af2[mi], bfr2[ni], acc2[mi][ni], 0, 0, 0);
    }

#pragma unroll
    for (int mi = 0; mi < 2; ++mi) {
        const int l = l0 + mi * 16 + quad * 4;
#pragma unroll
        for (int ni = 0; ni < 4; ++ni) {
            const int o = 64 * w + ni * 16 + mrow;
            *(float4*)&Y[((size_t)b * DOUT + o) * LL + l] = *(float4*)&acc2[mi][ni];
        }
    }
}

// ---------------------------------------------------------------------------
// k_dadd: correctness fallback Y += D @ u. Self-checks its 16 D-rows and
// early-exits when all-zero.
// ---------------------------------------------------------------------------
__global__ __launch_bounds__(256) void k_dadd(const float* __restrict__ Dm,
                                              const float* __restrict__ u,
                                              float* __restrict__ Y) {
    __shared__ int nz;
    if (threadIdx.x == 0) nz = 0;
    __syncthreads();
    const int o0 = blockIdx.x * 16;
    {
        const float4* dp = (const float4*)(Dm + (size_t)o0 * DI);
        int any = 0;
#pragma unroll
        for (int k = 0; k < 4; ++k) {
            float4 v = dp[threadIdx.x + k * 256];
            any |= (v.x != 0.f || v.y != 0.f || v.z != 0.f || v.w != 0.f);
        }
        if (any) atomicOr(&nz, 1);
    }
    __syncthreads();
    if (nz == 0) return;
    const int o = o0 + (threadIdx.x >> 4);
    const int li = threadIdx.x & 15;
    const int b = blockIdx.y;
    for (int lc = 0; lc < LL / 16; ++lc) {
        const int l = lc * 16 + li;
        float s = 0.f;
        for (int i = 0; i < DI; ++i)
            s += Dm[o * DI + i] * u[((size_t)b * DI + i) * LL + l];
        Y[((size_t)b * DOUT + o) * LL + l] += s;
    }
}

// ---------------------------------------------------------------------------
extern "C" void kernel_launch(void* const* d_in, const int* in_sizes, int n_in,
                              void* d_out, int out_size, void* d_ws, size_t ws_size,
                              hipStream_t stream) {
    const float* u  = (const float*)d_in[0];
    const float* Au = (const float*)d_in[1];
    const float* Bm = (const float*)d_in[2];
    const float* Cm = (const float*)d_in[3];
    const float* Dm = (const float*)d_in[4];
    const float* h0 = (const float*)d_in[5];
    float* Y = (float*)d_out;

    char* p = (char*)d_ws;
    float* finals  = (float*)p;  p += (size_t)CH * BS * 4;
    float* apow    = (float*)p;  p += (size_t)(CT + 1) * DS * 4;
    ushort* Bmb    = (ushort*)p; p += (size_t)DS * DI * 2;
    ushort* Cmb    = (ushort*)p; p += (size_t)DOUT * DS * 2;

    k_prep<<<dim3(256), 256, 0, stream>>>(Au, apow, Bm, Cm, Bmb, Cmb);
    k_finals<<<dim3(CH, BZ), 256, 0, stream>>>(u, Bmb, apow, finals);
    k_mainB<<<dim3(CH, BZ), 256, 0, stream>>>(u, Bmb, Cmb, apow, h0, finals, Y);
    k_dadd<<<dim3(DOUT / 16, BZ), 256, 0, stream>>>(Dm, u, Y);
}

// Round 10
// 159.161 us; speedup vs baseline: 1.4764x; 1.4764x over previous
//
#include <hip/hip_runtime.h>
#include <math.h>

// SimpleSSM: u(B,DI,L) f32, A(S), B_mat(S,DI), C_mat(DO,S), D_mat(DO,DI), h0(S)
#define BZ 8
#define DI 256
#define DS 512
#define DOUT 256
#define LL 4096
#define BS (BZ * DS)   // 4096
#define CH 64          // number of 64-wide l-chunks
#define CT 64          // chunk length
#define XST 520        // X LDS row stride in ushorts (512 + 8 pad)

typedef __bf16 bf16x8 __attribute__((ext_vector_type(8)));
typedef float f32x4 __attribute__((ext_vector_type(4)));
typedef unsigned short us8 __attribute__((ext_vector_type(8)));

#define WAITV(n) asm volatile("s_waitcnt vmcnt(" #n ")" ::: "memory")
#define WAITL0   asm volatile("s_waitcnt lgkmcnt(0)" ::: "memory")
#define SB0      __builtin_amdgcn_sched_barrier(0)

__device__ __forceinline__ ushort f2b(float f) {
    union { float f; unsigned u; } v; v.f = f;
    unsigned r = v.u + 0x7FFFu + ((v.u >> 16) & 1u);
    return (ushort)(r >> 16);
}
__device__ __forceinline__ float b2f(ushort h) {
    union { unsigned u; float f; } v; v.u = ((unsigned)h) << 16;
    return v.f;
}

__device__ __forceinline__ void gload16(const void* g, ushort* l) {
    __builtin_amdgcn_global_load_lds(
        (const __attribute__((address_space(1))) unsigned int*)g,
        (__attribute__((address_space(3))) unsigned int*)l,
        16, 0, 0);
}

// ---------------------------------------------------------------------------
// k_prep: apow table (a^j, j=0..64) + bf16 conversion of Bm/Cm. 256 blocks.
// ---------------------------------------------------------------------------
__global__ __launch_bounds__(256) void k_prep(const float* __restrict__ Au,
                                              float* __restrict__ apow,
                                              const float* __restrict__ Bm,
                                              const float* __restrict__ Cm,
                                              ushort* __restrict__ Bmb,
                                              ushort* __restrict__ Cmb) {
    const int t = blockIdx.x * 256 + threadIdx.x;
    const int n1 = DS * DI / 4, n2 = DOUT * DS / 4;
    if (t < n1) {
        float4 v = ((const float4*)Bm)[t];
        ushort4 o; o.x = f2b(v.x); o.y = f2b(v.y); o.z = f2b(v.z); o.w = f2b(v.w);
        ((ushort4*)Bmb)[t] = o;
    } else if (t < n1 + n2) {
        float4 v = ((const float4*)Cm)[t - n1];
        ushort4 o; o.x = f2b(v.x); o.y = f2b(v.y); o.z = f2b(v.z); o.w = f2b(v.w);
        ((ushort4*)Cmb)[t - n1] = o;
    }
    if (t < DS) {
        float x = Au[t];
        float sp = (x > 15.f) ? x : log1pf(expf(x));
        float ad = -sp;
        float p = 1.f;
        apow[t] = 1.f;
        for (int j = 1; j <= CT; ++j) { p *= ad; apow[j * DS + t] = p; }
    }
}

// ---------------------------------------------------------------------------
// k_finals: F_c[s] for ALL (c,b,s). One block per (chunk,b), FULL s=512 ->
// u staged exactly once grid-wide. 512 threads / 8 waves; wave w owns s-rows
// 64w..64w+63 (acc[4][4]). Counted-vmcnt GEMM1 + in-register weighted
// reduce: l = ni*16+mrow, weight a^(63-l) = a^(15-mrow)*(a^16)^(3-ni) ->
// Horner DESCENDS from acc[0]; butterfly over mrow.
// LDS 34 KB: Uc 3x[32i][64l]f32 @ush 0/4096/8192; Bt 2x[64l][40] @12288/14848.
// Grid (CH, BZ) = 512 blocks. __launch_bounds__(512,4): VGPR<=128,
// 2 blocks/CU = 16 waves/CU.
// vmcnt ledger (stage=1 event, af=4): prologue st0,st1; iter0 issues af0(4),
// st2(1) -> 7 outstanding, WAITV(6) drains st0. Steady: MFMA(it-1)'s
// compiler auto-wait (vmcnt(1)) transitively drains st(it) before xpose(it).
// ---------------------------------------------------------------------------
__global__ __launch_bounds__(512, 4) void k_finals(const float* __restrict__ u,
                                                   const ushort* __restrict__ Bmb,
                                                   const float* __restrict__ apow,
                                                   float* __restrict__ finals) {
    __shared__ ushort smem[17408];   // 34816 B
    const int tid = threadIdx.x;
    const int w = tid >> 6, lane = tid & 63;
    const int mrow = lane & 15, quad = lane >> 4;
    const int c0 = blockIdx.x, b = blockIdx.y;
    const int l0 = c0 * CT;

    f32x4 acc[4][4];
#pragma unroll
    for (int mi = 0; mi < 4; ++mi)
#pragma unroll
        for (int ni = 0; ni < 4; ++ni) acc[mi][ni] = (f32x4)0.f;

    // thread t stages 16B of u row i = t>>4 at col (t&15)*4 (wave w: rows 4w..4w+3)
    const float* usrc = u + ((size_t)b * DI + (tid >> 4)) * LL + l0 + (tid & 15) * 4;

    auto stageU = [&](int it) {           // 1 vmcnt event; buffer it%3
        gload16(usrc + (size_t)(it * 32) * LL, smem + (it % 3) * 4096 + w * 512);
    };
    auto xposeU = [&](int it) {           // wave-private rows 4w..4w+3
        const float* uf = (const float*)&smem[(it % 3) * 4096];
        const int bto = 12288 + (it & 1) * 2560;
        float v[4];
#pragma unroll
        for (int j = 0; j < 4; ++j) v[j] = uf[(4 * w + j) * 64 + lane];
        ushort4 o; o.x = f2b(v[0]); o.y = f2b(v[1]); o.z = f2b(v[2]); o.w = f2b(v[3]);
        *(ushort4*)&smem[bto + lane * 40 + 4 * w] = o;
    };

    stageU(0); stageU(1);
#pragma unroll
    for (int it = 0; it < DI / 32; ++it) {
        bf16x8 af[4];
#pragma unroll
        for (int mi = 0; mi < 4; ++mi)
            af[mi] = *(const bf16x8*)&Bmb[(size_t)(64 * w + mi * 16 + mrow) * DI + it * 32 + quad * 8];
        SB0;                               // af issued before stage/WAITV
        if (it + 2 < DI / 32) stageU(it + 2);
        if (it == 0) { WAITV(6); }         // drain stage(0)
        xposeU(it);
        WAITL0;
        __builtin_amdgcn_s_barrier();
        SB0;
        const int bto = 12288 + (it & 1) * 2560;
        bf16x8 bfr[4];
#pragma unroll
        for (int ni = 0; ni < 4; ++ni)
            bfr[ni] = *(const bf16x8*)&smem[bto + (ni * 16 + mrow) * 40 + quad * 8];
#pragma unroll
        for (int mi = 0; mi < 4; ++mi)
#pragma unroll
            for (int ni = 0; ni < 4; ++ni)
                acc[mi][ni] = __builtin_amdgcn_mfma_f32_16x16x32_bf16(af[mi], bfr[ni], acc[mi][ni], 0, 0, 0);
        WAITL0;                            // Bt reads done before next xpose
        __builtin_amdgcn_s_barrier();
        SB0;
    }

    // weighted reduce: F = a^(15-mrow)*(((acc0*a16+acc1)*a16+acc2)*a16+acc3)
    float F[4][4];
#pragma unroll
    for (int mi = 0; mi < 4; ++mi) {
        const int sb = 64 * w + mi * 16 + quad * 4;
        f32x4 a16 = *(const f32x4*)&apow[16 * DS + sb];
        f32x4 wgt = *(const f32x4*)&apow[(size_t)(15 - mrow) * DS + sb];
#pragma unroll
        for (int r = 0; r < 4; ++r) {
            float h = acc[mi][0][r];
            h = h * a16[r] + acc[mi][1][r];
            h = h * a16[r] + acc[mi][2][r];
            h = h * a16[r] + acc[mi][3][r];
            F[mi][r] = wgt[r] * h;
        }
    }
#pragma unroll
    for (int d = 1; d < 16; d <<= 1)
#pragma unroll
        for (int mi = 0; mi < 4; ++mi)
#pragma unroll
            for (int r = 0; r < 4; ++r)
                F[mi][r] += __shfl_xor(F[mi][r], d);
    if (mrow == 0) {
#pragma unroll
        for (int mi = 0; mi < 4; ++mi) {
            f32x4 o; o[0] = F[mi][0]; o[1] = F[mi][1]; o[2] = F[mi][2]; o[3] = F[mi][3];
            *(f32x4*)&finals[(size_t)c0 * BS + (size_t)b * DS + 64 * w + mi * 16 + quad * 4] = o;
        }
    }
}

// ---------------------------------------------------------------------------
// k_mainB: CT=64 tile (round-8 arithmetic intensity) at 512 threads/8 waves
// -> 2 blocks/CU x 8 waves = 4 waves/SIMD (round 8 had 2: the latency wall).
// Phases: prologue staging + exact batched carry (overlapped) -> GEMM1
// (counted-vmcnt, wave w owns s 64w..64w+63) -> X-store -> scan (512 states,
// 1/thread, reads batched by 8) -> correction -> GEMM2 (wave w owns o
// 32w..32w+31) -> Y.
// LDS (ush): staging overlay Uc 3x4096 @0, Bt 2x2560 @12288 (inside X);
// X [64][520] = [0,33280); crl f32[512] @33280. Total 68608 B.
// Grid (CH, BZ) = 512 blocks.
// ---------------------------------------------------------------------------
__global__ __launch_bounds__(512, 4) void k_mainB(const float* __restrict__ u,
                                                  const ushort* __restrict__ Bmb,
                                                  const ushort* __restrict__ Cmb,
                                                  const float* __restrict__ apow,
                                                  const float* __restrict__ h0,
                                                  const float* __restrict__ finals,
                                                  float* __restrict__ Y) {
    __shared__ ushort smem[34304];        // 68608 B
    float* crl = (float*)&smem[33280];
    const int tid = threadIdx.x;
    const int w = tid >> 6, lane = tid & 63;
    const int mrow = lane & 15, quad = lane >> 4;
    const int c0 = blockIdx.x, b = blockIdx.y;
    const int l0 = c0 * CT;

    const float* usrc = u + ((size_t)b * DI + (tid >> 4)) * LL + l0 + (tid & 15) * 4;

    auto stageU = [&](int it) {
        gload16(usrc + (size_t)(it * 32) * LL, smem + (it % 3) * 4096 + w * 512);
    };
    auto xposeU = [&](int it) {
        const float* uf = (const float*)&smem[(it % 3) * 4096];
        const int bto = 12288 + (it & 1) * 2560;
        float v[4];
#pragma unroll
        for (int j = 0; j < 4; ++j) v[j] = uf[(4 * w + j) * 64 + lane];
        ushort4 o; o.x = f2b(v[0]); o.y = f2b(v[1]); o.z = f2b(v[2]); o.w = f2b(v[3]);
        *(ushort4*)&smem[bto + lane * 40 + 4 * w] = o;
    };

    // ---- prologue staging, then exact carry chain under its latency -------
    stageU(0); stageU(1);
    {
        const float aT = apow[CT * DS + tid];          // a^64, s = tid
        float cva = h0[tid];
        const float* fb = finals + (size_t)b * DS;
        int c = 0;
        for (; c + 8 <= c0; c += 8) {
            float fa[8];
#pragma unroll
            for (int j = 0; j < 8; ++j) fa[j] = fb[(size_t)(c + j) * BS + tid];
#pragma unroll
            for (int j = 0; j < 8; ++j) cva = aT * cva + fa[j];
        }
        for (; c < c0; ++c) cva = aT * cva + fb[(size_t)c * BS + tid];
        crl[tid] = cva;
    }

    // ---- GEMM1: Bu, s512 x l64; wave w -> s 64w..64w+63 -------------------
    f32x4 acc1[4][4];
#pragma unroll
    for (int mi = 0; mi < 4; ++mi)
#pragma unroll
        for (int ni = 0; ni < 4; ++ni) acc1[mi][ni] = (f32x4)0.f;

#pragma unroll
    for (int it = 0; it < DI / 32; ++it) {
        bf16x8 af[4];
#pragma unroll
        for (int mi = 0; mi < 4; ++mi)
            af[mi] = *(const bf16x8*)&Bmb[(size_t)(64 * w + mi * 16 + mrow) * DI + it * 32 + quad * 8];
        SB0;
        if (it + 2 < DI / 32) stageU(it + 2);
        if (it == 0) { WAITV(6); }
        xposeU(it);
        WAITL0;
        __builtin_amdgcn_s_barrier();
        SB0;
        const int bto = 12288 + (it & 1) * 2560;
        bf16x8 bfr[4];
#pragma unroll
        for (int ni = 0; ni < 4; ++ni)
            bfr[ni] = *(const bf16x8*)&smem[bto + (ni * 16 + mrow) * 40 + quad * 8];
#pragma unroll
        for (int mi = 0; mi < 4; ++mi)
#pragma unroll
            for (int ni = 0; ni < 4; ++ni)
                acc1[mi][ni] = __builtin_amdgcn_mfma_f32_16x16x32_bf16(af[mi], bfr[ni], acc1[mi][ni], 0, 0, 0);
        WAITL0;
        __builtin_amdgcn_s_barrier();
        SB0;
    }
    __syncthreads();   // full drain before X-store overwrites staging region

    // ---- store acc1 -> X[l][s] (bf16, transposed) -------------------------
#pragma unroll
    for (int mi = 0; mi < 4; ++mi) {
        const int sloc = 64 * w + mi * 16 + quad * 4;
#pragma unroll
        for (int ni = 0; ni < 4; ++ni) {
            const int lloc = ni * 16 + mrow;
            f32x4 v = acc1[mi][ni];
            ushort4 o; o.x = f2b(v[0]); o.y = f2b(v[1]); o.z = f2b(v[2]); o.w = f2b(v[3]);
            *(ushort4*)&smem[lloc * XST + sloc] = o;
        }
    }
    __syncthreads();

    // ---- scan over l (64 steps), 1 state/thread, reads batched by 8 -------
    {
        const float av = apow[DS + tid];
        float x0 = 0.f;
        ushort* pp = &smem[tid];
#pragma unroll
        for (int bt = 0; bt < CT / 8; ++bt) {
            ushort v[8];
#pragma unroll
            for (int j = 0; j < 8; ++j) v[j] = pp[(bt * 8 + j) * XST];
#pragma unroll
            for (int j = 0; j < 8; ++j) {
                x0 = av * x0 + b2f(v[j]);
                v[j] = f2b(x0);
            }
#pragma unroll
            for (int j = 0; j < 8; ++j) pp[(bt * 8 + j) * XST] = v[j];
        }
    }
    __syncthreads();

    // ---- correction: X[l][s] += apow[l+1][s] * crl[s] ---------------------
    {
        const int lr = tid >> 3, g = tid & 7;   // 64 rows x 8 groups
#pragma unroll
        for (int cc = 0; cc < 8; ++cc) {
            const int s = g * 64 + cc * 8;
            us8 x = *(const us8*)&smem[lr * XST + s];
            float4 a1 = *(const float4*)&apow[(size_t)(lr + 1) * DS + s];
            float4 a2 = *(const float4*)&apow[(size_t)(lr + 1) * DS + s + 4];
            float4 c1 = *(const float4*)&crl[s];
            float4 c2 = *(const float4*)&crl[s + 4];
            us8 o;
            o[0] = f2b(b2f(x[0]) + a1.x * c1.x);
            o[1] = f2b(b2f(x[1]) + a1.y * c1.y);
            o[2] = f2b(b2f(x[2]) + a1.z * c1.z);
            o[3] = f2b(b2f(x[3]) + a1.w * c1.w);
            o[4] = f2b(b2f(x[4]) + a2.x * c2.x);
            o[5] = f2b(b2f(x[5]) + a2.y * c2.y);
            o[6] = f2b(b2f(x[6]) + a2.z * c2.z);
            o[7] = f2b(b2f(x[7]) + a2.w * c2.w);
            *(us8*)&smem[lr * XST + s] = o;
        }
    }
    __syncthreads();

    // ---- GEMM2: Y = C @ Xc, o256 x l64; wave w -> o 32w..32w+31 -----------
    f32x4 acc2[4][2];
#pragma unroll
    for (int mi = 0; mi < 4; ++mi)
#pragma unroll
        for (int ni = 0; ni < 2; ++ni) acc2[mi][ni] = (f32x4)0.f;

#pragma unroll
    for (int it = 0; it < DS / 32; ++it) {
        bf16x8 af2[4], bfr2[2];
#pragma unroll
        for (int mi = 0; mi < 4; ++mi)
            af2[mi] = *(const bf16x8*)&smem[(mi * 16 + mrow) * XST + it * 32 + quad * 8];
#pragma unroll
        for (int ni = 0; ni < 2; ++ni)
            bfr2[ni] = *(const bf16x8*)&Cmb[(size_t)(32 * w + ni * 16 + mrow) * DS + it * 32 + quad * 8];
#pragma unroll
        for (int mi = 0; mi < 4; ++mi)
#pragma unroll
            for (int ni = 0; ni < 2; ++ni)
                acc2[mi][ni] = __builtin_amdgcn_mfma_f32_16x16x32_bf16(af2[mi], bfr2[ni], acc2[mi][ni], 0, 0, 0);
    }

#pragma unroll
    for (int mi = 0; mi < 4; ++mi) {
        const int l = l0 + mi * 16 + quad * 4;
#pragma unroll
        for (int ni = 0; ni < 2; ++ni) {
            const int o = 32 * w + ni * 16 + mrow;
            *(float4*)&Y[((size_t)b * DOUT + o) * LL + l] = *(float4*)&acc2[mi][ni];
        }
    }
}

// ---------------------------------------------------------------------------
// k_dadd: correctness fallback Y += D @ u. Self-checks its 16 D-rows and
// early-exits when all-zero.
// ---------------------------------------------------------------------------
__global__ __launch_bounds__(256) void k_dadd(const float* __restrict__ Dm,
                                              const float* __restrict__ u,
                                              float* __restrict__ Y) {
    __shared__ int nz;
    if (threadIdx.x == 0) nz = 0;
    __syncthreads();
    const int o0 = blockIdx.x * 16;
    {
        const float4* dp = (const float4*)(Dm + (size_t)o0 * DI);
        int any = 0;
#pragma unroll
        for (int k = 0; k < 4; ++k) {
            float4 v = dp[threadIdx.x + k * 256];
            any |= (v.x != 0.f || v.y != 0.f || v.z != 0.f || v.w != 0.f);
        }
        if (any) atomicOr(&nz, 1);
    }
    __syncthreads();
    if (nz == 0) return;
    const int o = o0 + (threadIdx.x >> 4);
    const int li = threadIdx.x & 15;
    const int b = blockIdx.y;
    for (int lc = 0; lc < LL / 16; ++lc) {
        const int l = lc * 16 + li;
        float s = 0.f;
        for (int i = 0; i < DI; ++i)
            s += Dm[o * DI + i] * u[((size_t)b * DI + i) * LL + l];
        Y[((size_t)b * DOUT + o) * LL + l] += s;
    }
}

// ---------------------------------------------------------------------------
extern "C" void kernel_launch(void* const* d_in, const int* in_sizes, int n_in,
                              void* d_out, int out_size, void* d_ws, size_t ws_size,
                              hipStream_t stream) {
    const float* u  = (const float*)d_in[0];
    const float* Au = (const float*)d_in[1];
    const float* Bm = (const float*)d_in[2];
    const float* Cm = (const float*)d_in[3];
    const float* Dm = (const float*)d_in[4];
    const float* h0 = (const float*)d_in[5];
    float* Y = (float*)d_out;

    char* p = (char*)d_ws;
    float* finals  = (float*)p;  p += (size_t)CH * BS * 4;
    float* apow    = (float*)p;  p += (size_t)(CT + 1) * DS * 4;
    ushort* Bmb    = (ushort*)p; p += (size_t)DS * DI * 2;
    ushort* Cmb    = (ushort*)p; p += (size_t)DOUT * DS * 2;

    k_prep<<<dim3(256), 256, 0, stream>>>(Au, apow, Bm, Cm, Bmb, Cmb);
    k_finals<<<dim3(CH, BZ), 512, 0, stream>>>(u, Bmb, apow, finals);
    k_mainB<<<dim3(CH, BZ), 512, 0, stream>>>(u, Bmb, Cmb, apow, h0, finals, Y);
    k_dadd<<<dim3(DOUT / 16, BZ), 256, 0, stream>>>(Dm, u, Y);
}